// Round 1
// baseline (884.382 us; speedup 1.0000x reference)
//
#include <hip/hip_runtime.h>
#include <hip/hip_bf16.h>
#include <cstdint>
#include <cstddef>

// Problem constants (fixed by the reference):
//   G=2048 graphs, N_PER=64, K=16, H=1024, GH=512, T=65536
//   M = G*K = 32768 selected rows
//   GEMM1: [M,1536] @ dense_w^T[1536,1024], tanh  -> x1 bf16
//   GEMM2: [M,1024] @ out_w^T [1024,1024], +bias  -> out f32
#define MROWS 32768
#define HDIM  1024
#define GHDIM 512
#define KA    1536   // H + GH
#define KB    1024

typedef short bf16x8 __attribute__((ext_vector_type(8)));
typedef float f32x4  __attribute__((ext_vector_type(4)));

__device__ __forceinline__ unsigned short f2bf(float f) {
  union { float f; unsigned u; } c; c.f = f;
  unsigned r = c.u + 0x7FFFu + ((c.u >> 16) & 1u);   // RTNE
  return (unsigned short)(r >> 16);
}

#define GLOAD16(g, l)                                                     \
  __builtin_amdgcn_global_load_lds(                                       \
      (const __attribute__((address_space(1))) unsigned int*)(g),         \
      (__attribute__((address_space(3))) unsigned int*)(l), 16, 0, 0)

// ---------------------------------------------------------------------------
// Kernel 1: lm_row[m] = index of m-th True in choice_mask.
// Single block, 1024 threads, 64 elements each. Runtime-detects whether the
// bool mask was uploaded as 1 byte/elem or 4 bytes/elem (count of nonzero
// bytes in first 65536 bytes == 32768 iff u8 storage; i32 storage gives
// <=16384 there).
// ---------------------------------------------------------------------------
__global__ void build_lm_rows(const unsigned char* __restrict__ mask8,
                              int* __restrict__ lm_row) {
  __shared__ int sh[1024];
  __shared__ int flag;
  const int t = threadIdx.x;

  int c8 = 0;
  for (int i = 0; i < 64; ++i) c8 += (mask8[t * 64 + i] != 0) ? 1 : 0;
  sh[t] = c8;
  __syncthreads();
  for (int s = 512; s > 0; s >>= 1) {
    if (t < s) sh[t] += sh[t + s];
    __syncthreads();
  }
  if (t == 0) flag = (sh[0] == MROWS) ? 1 : 0;
  __syncthreads();
  const int isU8 = flag;
  const int* mask32 = (const int*)mask8;

  int cnt = 0;
  for (int i = 0; i < 64; ++i) {
    int idx = t * 64 + i;
    bool v = isU8 ? (mask8[idx] != 0) : (mask32[idx] != 0);
    cnt += v ? 1 : 0;
  }
  __syncthreads();
  sh[t] = cnt;
  __syncthreads();
  // inclusive Hillis-Steele scan
  for (int s = 1; s < 1024; s <<= 1) {
    int v = sh[t];
    int add = (t >= s) ? sh[t - s] : 0;
    __syncthreads();
    sh[t] = v + add;
    __syncthreads();
  }
  int pre = sh[t] - cnt;  // exclusive prefix
  for (int i = 0; i < 64; ++i) {
    int idx = t * 64 + i;
    bool v = isU8 ? (mask8[idx] != 0) : (mask32[idx] != 0);
    if (v) {
      if (pre < MROWS) lm_row[pre] = idx;
      ++pre;
    }
  }
}

// ---------------------------------------------------------------------------
// Kernel 2: gnn_row[g*16 + rank] = g*64 + v for each valid node value v in
// top_mask[g*64..]; rank = ascending rank among the graph's 16 valid values.
// One wave per graph; 64-bit value-occupancy mask via shfl-OR + popcount.
// ---------------------------------------------------------------------------
__global__ void build_gnn_rows(const int* __restrict__ top_mask,
                               int* __restrict__ gnn_row) {
  const int g = blockIdx.x * 4 + (threadIdx.x >> 6);
  const int lane = threadIdx.x & 63;
  int tm = top_mask[g * 64 + lane];
  bool valid = (tm != -100);
  unsigned long long bit = valid ? (1ULL << tm) : 0ULL;
  #pragma unroll
  for (int s = 1; s < 64; s <<= 1) bit |= __shfl_xor(bit, s);
  if (valid) {
    int rank = __popcll(bit & ((1ULL << tm) - 1ULL));
    gnn_row[g * 16 + rank] = g * 64 + tm;
  }
}

// ---------------------------------------------------------------------------
// Kernel 3: gather + f32->bf16: A[m] = concat(lm_x[lm_row[m]], gnn_x[gnn_row[m]])
// One block per row, 256 threads: 1 float4 (lm) + 1 float2 (gnn) per thread.
// ---------------------------------------------------------------------------
__global__ void gather_A(const float* __restrict__ lm_x,
                         const float* __restrict__ gnn_x,
                         const int* __restrict__ lm_row,
                         const int* __restrict__ gnn_row,
                         unsigned short* __restrict__ A) {
  const int m = blockIdx.x, t = threadIdx.x;
  const int lr = lm_row[m], gr = gnn_row[m];
  float4 v = ((const float4*)(lm_x + (size_t)lr * HDIM))[t];
  unsigned long long p =
      (unsigned long long)f2bf(v.x) | ((unsigned long long)f2bf(v.y) << 16) |
      ((unsigned long long)f2bf(v.z) << 32) | ((unsigned long long)f2bf(v.w) << 48);
  ((unsigned long long*)(A + (size_t)m * KA))[t] = p;
  float2 v2 = ((const float2*)(gnn_x + (size_t)gr * GHDIM))[t];
  unsigned p2 = (unsigned)f2bf(v2.x) | ((unsigned)f2bf(v2.y) << 16);
  ((unsigned*)(A + (size_t)m * KA + HDIM))[t] = p2;
}

// ---------------------------------------------------------------------------
// Kernel 4: f32 -> bf16 weight conversion (layout preserved), float4-wide.
// ---------------------------------------------------------------------------
__global__ void cvt_w(const float* __restrict__ src,
                      unsigned short* __restrict__ dst, int n4) {
  int i = blockIdx.x * 256 + threadIdx.x;
  if (i >= n4) return;
  float4 v = ((const float4*)src)[i];
  unsigned long long p =
      (unsigned long long)f2bf(v.x) | ((unsigned long long)f2bf(v.y) << 16) |
      ((unsigned long long)f2bf(v.z) << 32) | ((unsigned long long)f2bf(v.w) << 48);
  ((unsigned long long*)dst)[i] = p;
}

// ---------------------------------------------------------------------------
// Kernel 5: GEMM  C[m][n] = sum_k A[m][k] * B[n][k]   (both row-major, K-contig)
// 128x128 tile, BK=64, 4 waves (2x2), per-wave 4x4 frags of 16x16x32 bf16 MFMA.
// global_load_lds width-16 staging, linear LDS dest; XOR swizzle done by
// permuting the per-lane GLOBAL source block (rule: linear dest + inv-swz src
// + swz read) -> conflict-free ds_read_b128.
// EPI 0: tanh(acc + bias[n]) -> bf16 store   EPI 1: acc + bias[n] -> f32 store
// ---------------------------------------------------------------------------
template <int KD, int EPI>
__global__ __launch_bounds__(256) void gemm_bt(
    const unsigned short* __restrict__ A, const unsigned short* __restrict__ B,
    const float* __restrict__ bias, void* __restrict__ out) {
  __shared__ __attribute__((aligned(16))) unsigned short As[128 * 64];
  __shared__ __attribute__((aligned(16))) unsigned short Bs[128 * 64];

  const int tid = threadIdx.x;
  const int bid = blockIdx.x;
  const int ntile = bid & 7;   // 8 N-panels -> 8 XCDs (L2-resident B panel)
  const int mtile = bid >> 3;  // 256 M-tiles
  const int w = tid >> 6, l = tid & 63;
  const int lr = l & 15, lh = l >> 4;
  const int wm = w >> 1, wn = w & 1;
  const int m0 = mtile * 128, n0 = ntile * 128;

  f32x4 acc[4][4] = {};

  for (int kt = 0; kt < KD; kt += 64) {
    #pragma unroll
    for (int i = 0; i < 4; ++i) {
      const int lin = (w * 4 + i) * 1024 + l * 16;  // linear byte in 16KB tile
      const int row = lin >> 7;                      // tile row (128B rows)
      const int slot = (lin >> 4) & 7;               // 16B slot within row
      const int blk = slot ^ (row & 7);              // inverse-swizzled source
      GLOAD16(A + (size_t)(m0 + row) * KD + kt + blk * 8,
              (char*)As + (w * 4 + i) * 1024);
      GLOAD16(B + (size_t)(n0 + row) * KD + kt + blk * 8,
              (char*)Bs + (w * 4 + i) * 1024);
    }
    __syncthreads();

    #pragma unroll
    for (int kk = 0; kk < 2; ++kk) {
      bf16x8 af[4], bfr[4];
      #pragma unroll
      for (int mi = 0; mi < 4; ++mi) {
        const int row = wm * 64 + mi * 16 + lr;
        const int slot = (kk * 4 + lh) ^ (row & 7);  // swizzled read
        af[mi] = *(const bf16x8*)((const char*)As + row * 128 + slot * 16);
      }
      #pragma unroll
      for (int ni = 0; ni < 4; ++ni) {
        const int row = wn * 64 + ni * 16 + lr;
        const int slot = (kk * 4 + lh) ^ (row & 7);
        bfr[ni] = *(const bf16x8*)((const char*)Bs + row * 128 + slot * 16);
      }
      #pragma unroll
      for (int mi = 0; mi < 4; ++mi)
        #pragma unroll
        for (int ni = 0; ni < 4; ++ni)
          acc[mi][ni] = __builtin_amdgcn_mfma_f32_16x16x32_bf16(
              af[mi], bfr[ni], acc[mi][ni], 0, 0, 0);
    }
    __syncthreads();
  }

  // Epilogue. C/D frag layout (m89-verified): col = lane&15, row = (lane>>4)*4+reg
  if (EPI == 0) {
    unsigned short* x1 = (unsigned short*)out;
    #pragma unroll
    for (int ni = 0; ni < 4; ++ni) {
      const int col = n0 + wn * 64 + ni * 16 + lr;
      const float bb = bias[col];
      #pragma unroll
      for (int mi = 0; mi < 4; ++mi) {
        const int rowb = m0 + wm * 64 + mi * 16 + lh * 4;
        #pragma unroll
        for (int r = 0; r < 4; ++r) {
          float v = tanhf(acc[mi][ni][r] + bb);
          x1[(size_t)(rowb + r) * HDIM + col] = f2bf(v);
        }
      }
    }
  } else {
    float* O = (float*)out;
    #pragma unroll
    for (int ni = 0; ni < 4; ++ni) {
      const int col = n0 + wn * 64 + ni * 16 + lr;
      const float bb = bias[col];
      #pragma unroll
      for (int mi = 0; mi < 4; ++mi) {
        const int rowb = m0 + wm * 64 + mi * 16 + lh * 4;
        #pragma unroll
        for (int r = 0; r < 4; ++r)
          O[(size_t)(rowb + r) * HDIM + col] = acc[mi][ni][r] + bb;
      }
    }
  }
}

// ---------------------------------------------------------------------------
extern "C" void kernel_launch(void* const* d_in, const int* in_sizes, int n_in,
                              void* d_out, int out_size, void* d_ws,
                              size_t ws_size, hipStream_t stream) {
  const float* lm_x    = (const float*)d_in[0];
  const void*  choice  = d_in[1];
  const float* gnn_x   = (const float*)d_in[2];
  const int*   top_mask = (const int*)d_in[3];
  // d_in[4]=ptr (uniform, unused), d_in[5]=k (=16, hardcoded)
  const float* dense_w = (const float*)d_in[6];
  const float* dense_b = (const float*)d_in[7];
  const float* out_w   = (const float*)d_in[8];
  const float* out_b   = (const float*)d_in[9];
  float* out = (float*)d_out;

  // workspace layout (total ~165.3 MB)
  char* ws = (char*)d_ws;
  int* lm_row  = (int*)ws;                                   // 128 KB
  int* gnn_row = (int*)(ws + 131072);                        // 128 KB
  unsigned short* Abf = (unsigned short*)(ws + 262144);      // 96 MB
  unsigned short* Wd  = Abf + (size_t)MROWS * KA;            // 3 MB
  unsigned short* Wo  = Wd + (size_t)HDIM * KA;              // 2 MB
  unsigned short* x1  = Wo + (size_t)HDIM * KB;              // 64 MB

  build_lm_rows<<<1, 1024, 0, stream>>>((const unsigned char*)choice, lm_row);
  build_gnn_rows<<<512, 256, 0, stream>>>(top_mask, gnn_row);
  cvt_w<<<(HDIM * KA / 4 + 255) / 256, 256, 0, stream>>>(dense_w, Wd, HDIM * KA / 4);
  cvt_w<<<(HDIM * KB / 4 + 255) / 256, 256, 0, stream>>>(out_w, Wo, HDIM * KB / 4);
  gather_A<<<MROWS, 256, 0, stream>>>(lm_x, gnn_x, lm_row, gnn_row, Abf);

  gemm_bt<KA, 0><<<2048, 256, 0, stream>>>(Abf, Wd, dense_b, x1);
  gemm_bt<KB, 1><<<2048, 256, 0, stream>>>(x1, Wo, out_b, out);
}